// Round 1
// baseline (405.952 us; speedup 1.0000x reference)
//
#include <hip/hip_runtime.h>

#define NB 1024
#define NN 128
#define KK 32
#define DM 64

constexpr float Y0 = 0.28209479177387814f;
constexpr float Y1 = 0.4886025119029199f;

// ws layout (floats):
//   feats: [NB*NN][8]  (px,py,pz,vx,vy,vz,|v|,mass)   4 MB
//   com:   [NB][4]                                     16 KB
//   nbr:   [NB*NN][32] (int)                           16 MB

__global__ __launch_bounds__(128) void k1_prep(const float* __restrict__ in,
        float* __restrict__ feats, float* __restrict__ com, float* __restrict__ out)
{
    const int b = blockIdx.x, t = threadIdx.x;
    const float* p = in + ((size_t)b*NN + t)*7;
    const float m  = p[0];
    const float lx = p[1], ly = p[2], lz = p[3];
    const float vx = p[4], vy = p[5], vz = p[6];
    float w=m, wx=m*lx, wy=m*ly, wz=m*lz;
    #pragma unroll
    for (int s=1; s<64; s<<=1) {
        w  += __shfl_xor(w,  s);
        wx += __shfl_xor(wx, s);
        wy += __shfl_xor(wy, s);
        wz += __shfl_xor(wz, s);
    }
    __shared__ float red[2][4];
    if ((t & 63) == 0) { int wi=t>>6; red[wi][0]=w; red[wi][1]=wx; red[wi][2]=wy; red[wi][3]=wz; }
    __syncthreads();
    const float Wt = red[0][0]+red[1][0];
    const float cx = (red[0][1]+red[1][1])/Wt;
    const float cy = (red[0][2]+red[1][2])/Wt;
    const float cz = (red[0][3]+red[1][3])/Wt;
    const float px = lx-cx, py = ly-cy, pz = lz-cz;
    const float va = sqrtf(vx*vx+vy*vy+vz*vz);
    float4* f4 = (float4*)(feats + ((size_t)b*NN + t)*8);
    f4[0] = make_float4(px,py,pz,vx);
    f4[1] = make_float4(vy,vz,va,m);
    if (t==0) { float4* c4=(float4*)(com + (size_t)b*4); *c4 = make_float4(cx,cy,cz,0.f); }
    // second output: zeros(B)
    if (b < 8) out[(size_t)NB*NN*3 + (size_t)b*128 + t] = 0.f;
}

__global__ __launch_bounds__(256) void k2_knn(const float* __restrict__ feats, int* __restrict__ nbr)
{
    const int t  = threadIdx.x;
    const int nl = t & 127;
    const int hb = t >> 7;                 // which of 2 batches in this block
    const int b  = blockIdx.x*2 + hb;
    __shared__ float px[2][128], py[2][128], pz[2][128];
    const size_t gn = (size_t)b*NN + nl;
    const float4 f0 = *(const float4*)(feats + gn*8);
    px[hb][nl]=f0.x; py[hb][nl]=f0.y; pz[hb][nl]=f0.z;
    __syncthreads();
    const float mx=f0.x, my=f0.y, mz=f0.z;
    unsigned long long key[32];            // descending-sorted, key[0] = max
    #pragma unroll
    for (int e=0;e<32;e++) key[e] = ~0ULL;
    #pragma unroll 1
    for (int j=0;j<128;j++) {
        const float dx = px[hb][j]-mx, dy = py[hb][j]-my, dz = pz[hb][j]-mz;
        float d2 = dx*dx + dy*dy + dz*dz;
        if (j == nl) d2 = __int_as_float(0x7f800000);   // +inf on diagonal, as reference
        const unsigned long long nk =
            ((unsigned long long)__float_as_uint(d2) << 32) | (unsigned)j;
        if (nk < key[0]) {
            #pragma unroll
            for (int e=0;e<31;e++) {
                const unsigned long long hi = (key[e+1] > nk) ? key[e+1] : nk;
                key[e] = (key[e] < hi) ? key[e] : hi;
            }
            key[31] = (key[31] < nk) ? key[31] : nk;
        }
    }
    int* o = nbr + gn*32;
    #pragma unroll
    for (int e=0;e<32;e++) o[e] = (int)(unsigned)key[e];
}

__global__ __launch_bounds__(256) void k3_main(const float* __restrict__ feats,
        const int* __restrict__ nbr, const float* __restrict__ Wm,
        const float* __restrict__ Wo, const float* __restrict__ com,
        float* __restrict__ out)
{
    const int b = blockIdx.x, t = threadIdx.x;
    __shared__ float sF[128][8];
    __shared__ float sWm[20][64];
    __shared__ float sWo[75][3];
    __shared__ float sXs[128][68];   // padded to break bank aliasing on gathers
    __shared__ int   sNb[128][32];
    for (int i=t;i<1024;i+=256) ((float*)sF)[i]  = feats[(size_t)b*1024 + i];
    for (int i=t;i<1280;i+=256) ((float*)sWm)[i] = Wm[i];
    for (int i=t;i<225; i+=256) ((float*)sWo)[i] = Wo[i];
    for (int i=t;i<4096;i+=256) ((int*)sNb)[i]   = nbr[(size_t)b*4096 + i];
    __syncthreads();
    // Xs[n][d] = x[n](7) . Wm[0:7, d]   (src-dependent part of the msg MLP)
    for (int i=t;i<8192;i+=256) {
        const int n = i>>6, d = i&63;
        float s = 0.f;
        #pragma unroll
        for (int k=0;k<7;k++) s = fmaf(sF[n][k], sWm[k][d], s);
        sXs[n][d] = s;
    }
    __syncthreads();

    const int dsub = t & 7;          // 8 threads per node, 8 dims each
    const int ng   = t >> 3;         // 0..31 node within chunk
    const int d0   = dsub*8;
    float wc[5][8];                  // rows 15..19 (u_x,u_y,u_z,dist,pm), my columns
    #pragma unroll
    for (int r=0;r<5;r++)
        #pragma unroll
        for (int c=0;c<8;c++) wc[r][c] = sWm[15+r][d0+c];
    const float cmx = com[(size_t)b*4+0], cmy = com[(size_t)b*4+1], cmz = com[(size_t)b*4+2];

    #pragma unroll 1
    for (int ch=0; ch<4; ++ch) {
        const int n = ch*32 + ng;
        const float pdx=sF[n][0], pdy=sF[n][1], pdz=sF[n][2];
        const float mdm=sF[n][7];
        // dst-dependent part + Y0*row14 bias
        float xdb[8];
        #pragma unroll
        for (int c=0;c<8;c++) {
            float s = Y0 * sWm[14][d0+c];
            #pragma unroll
            for (int k=0;k<7;k++) s = fmaf(sF[n][k], sWm[7+k][d0+c], s);
            xdb[c] = s;
        }
        float acc[8];
        #pragma unroll
        for (int c=0;c<8;c++) acc[c]=0.f;
        float sux=0.f, suy=0.f, suz=0.f;   // sum of Y1*u over edges
        #pragma unroll 2
        for (int e=0;e<32;e++) {
            const int sidx = sNb[n][e];
            const float rx = sF[sidx][0]-pdx, ry = sF[sidx][1]-pdy, rz = sF[sidx][2]-pdz;
            const float r2 = rx*rx+ry*ry+rz*rz;
            const float dist = sqrtf(r2);
            const float inv = Y1 / fmaxf(dist, 1e-12f);
            const float ux = rx*inv, uy = ry*inv, uz = rz*inv;
            sux += ux; suy += uy; suz += uz;
            const float pm = sF[sidx][7]*mdm;
            const float* xsrow = &sXs[sidx][d0];
            #pragma unroll
            for (int c=0;c<8;c++) {
                float v = xdb[c] + xsrow[c];
                v = fmaf(ux,   wc[0][c], v);
                v = fmaf(uy,   wc[1][c], v);
                v = fmaf(uz,   wc[2][c], v);
                v = fmaf(dist, wc[3][c], v);
                v = fmaf(pm,   wc[4][c], v);
                acc[c] += fmaxf(v, 0.f);
            }
        }
        // partial output projection from my 8 agg dims
        float p0=0.f,p1=0.f,p2=0.f;
        #pragma unroll
        for (int c=0;c<8;c++) {
            const float a = acc[c]*(1.0f/32.0f);
            p0 = fmaf(a, sWo[11+d0+c][0], p0);
            p1 = fmaf(a, sWo[11+d0+c][1], p1);
            p2 = fmaf(a, sWo[11+d0+c][2], p2);
        }
        #pragma unroll
        for (int s=1;s<8;s<<=1) {
            p0 += __shfl_xor(p0, s);
            p1 += __shfl_xor(p1, s);
            p2 += __shfl_xor(p2, s);
        }
        if (dsub == 0) {
            const float vx=sF[n][3], vy=sF[n][4], vz=sF[n][5], va=sF[n][6];
            const float vinv = Y1 / fmaxf(va, 1e-12f);
            const float na0 = 2.f*Y0;
            const float na1 = sux*(1.f/32.f) + vx*vinv;
            const float na2 = suy*(1.f/32.f) + vy*vinv;
            const float na3 = suz*(1.f/32.f) + vz*vinv;
            const float x[7] = {pdx,pdy,pdz,vx,vy,vz,va};
            #pragma unroll
            for (int k=0;k<7;k++) {
                p0 = fmaf(x[k], sWo[k][0], p0);
                p1 = fmaf(x[k], sWo[k][1], p1);
                p2 = fmaf(x[k], sWo[k][2], p2);
            }
            p0 += na0*sWo[7][0] + na1*sWo[8][0] + na2*sWo[9][0] + na3*sWo[10][0];
            p1 += na0*sWo[7][1] + na1*sWo[8][1] + na2*sWo[9][1] + na3*sWo[10][1];
            p2 += na0*sWo[7][2] + na1*sWo[8][2] + na2*sWo[9][2] + na3*sWo[10][2];
            float* op = out + ((size_t)b*NN + n)*3;
            op[0] = pdx + cmx + p0;   // centered loc + com + shift = orig loc + shift
            op[1] = pdy + cmy + p1;
            op[2] = pdz + cmz + p2;
        }
    }
}

extern "C" void kernel_launch(void* const* d_in, const int* in_sizes, int n_in,
                              void* d_out, int out_size, void* d_ws, size_t ws_size,
                              hipStream_t stream)
{
    const float* in = (const float*)d_in[0];
    const float* Wm = (const float*)d_in[1];
    const float* Wo = (const float*)d_in[2];
    float* out = (float*)d_out;
    float* feats = (float*)d_ws;                       // NB*NN*8 floats
    float* com   = feats + (size_t)NB*NN*8;            // NB*4 floats
    int*   nbr   = (int*)(com + (size_t)NB*4);         // NB*NN*32 ints

    k1_prep<<<NB,    128, 0, stream>>>(in, feats, com, out);
    k2_knn <<<NB/2,  256, 0, stream>>>(feats, nbr);
    k3_main<<<NB,    256, 0, stream>>>(feats, nbr, Wm, Wo, com, out);
}

// Round 2
// 238.998 us; speedup vs baseline: 1.6986x; 1.6986x over previous
//
#include <hip/hip_runtime.h>

#define NB 1024
#define NN 128
#define KK 32
#define DM 64

constexpr float Y0 = 0.28209479177387814f;
constexpr float Y1 = 0.4886025119029199f;

// ws layout (floats):
//   feats: [NB*NN][8]  (px,py,pz,vx,vy,vz,|v|,mass)   4 MB
//   com:   [NB][4]                                     16 KB
//   nbr:   [NB*NN][32] (int)                           16 MB

__global__ __launch_bounds__(128) void k1_prep(const float* __restrict__ in,
        float* __restrict__ feats, float* __restrict__ com, float* __restrict__ out)
{
    const int b = blockIdx.x, t = threadIdx.x;
    const float* p = in + ((size_t)b*NN + t)*7;
    const float m  = p[0];
    const float lx = p[1], ly = p[2], lz = p[3];
    const float vx = p[4], vy = p[5], vz = p[6];
    float w=m, wx=m*lx, wy=m*ly, wz=m*lz;
    #pragma unroll
    for (int s=1; s<64; s<<=1) {
        w  += __shfl_xor(w,  s);
        wx += __shfl_xor(wx, s);
        wy += __shfl_xor(wy, s);
        wz += __shfl_xor(wz, s);
    }
    __shared__ float red[2][4];
    if ((t & 63) == 0) { int wi=t>>6; red[wi][0]=w; red[wi][1]=wx; red[wi][2]=wy; red[wi][3]=wz; }
    __syncthreads();
    const float Wt = red[0][0]+red[1][0];
    const float cx = (red[0][1]+red[1][1])/Wt;
    const float cy = (red[0][2]+red[1][2])/Wt;
    const float cz = (red[0][3]+red[1][3])/Wt;
    const float px = lx-cx, py = ly-cy, pz = lz-cz;
    const float va = sqrtf(vx*vx+vy*vy+vz*vz);
    float4* f4 = (float4*)(feats + ((size_t)b*NN + t)*8);
    f4[0] = make_float4(px,py,pz,vx);
    f4[1] = make_float4(vy,vz,va,m);
    if (t==0) { float4* c4=(float4*)(com + (size_t)b*4); *c4 = make_float4(cx,cy,cz,0.f); }
    // second output: zeros(B)
    if (b < 8) out[(size_t)NB*NN*3 + (size_t)b*128 + t] = 0.f;
}

// wave-per-node exact top-32 via ballot radix threshold search.
// 4 waves per block = 4 consecutive nodes (always same batch: 128 % 4 == 0).
__global__ __launch_bounds__(256) void k2_knn(const float* __restrict__ feats,
                                              int* __restrict__ nbr)
{
    const int lane = threadIdx.x & 63;
    const int g    = blockIdx.x*4 + (threadIdx.x >> 6);   // global node id
    const int b    = g >> 7, n = g & 127;
    const size_t base = (size_t)b*NN;

    const float4 c4 = *(const float4*)(feats + (base + n)*8);          // my node pos
    const float4 a4 = *(const float4*)(feats + (base + lane)*8);       // candidate j=lane
    const float4 b4 = *(const float4*)(feats + (base + 64 + lane)*8);  // candidate j=lane+64

    float dx = a4.x-c4.x, dy = a4.y-c4.y, dz = a4.z-c4.z;
    float d2a = dx*dx + dy*dy + dz*dz;
    dx = b4.x-c4.x; dy = b4.y-c4.y; dz = b4.z-c4.z;
    float d2b = dx*dx + dy*dy + dz*dz;
    if (lane == n)      d2a = __int_as_float(0x7f800000);
    if (lane + 64 == n) d2b = __int_as_float(0x7f800000);
    const unsigned u0 = __float_as_uint(d2a);
    const unsigned u1 = __float_as_uint(d2b);

    // bitwise binary search for T = 32nd smallest value (max P with count_less(P) <= 31)
    unsigned P = 0u;
    #pragma unroll 1
    for (int bit = 30; bit >= 0; --bit) {
        const unsigned Q = P | (1u << bit);
        const int cnt = __popcll(__ballot(u0 < Q)) + __popcll(__ballot(u1 < Q));
        if (cnt <= 31) P = Q;
    }
    const unsigned T = P;

    const unsigned long long lt = (1ULL << lane) - 1ULL;
    const unsigned long long m0 = __ballot(u0 < T), m1 = __ballot(u1 < T);
    const unsigned long long e0 = __ballot(u0 == T), e1 = __ballot(u1 == T);
    const int c0  = __popcll(m0);
    const int c   = c0 + __popcll(m1);
    const int rem = 32 - c;                    // >= 1 by construction
    int* o = nbr + (size_t)g*32;
    if (u0 <  T) o[__popcll(m0 & lt)] = lane;
    if (u1 <  T) o[c0 + __popcll(m1 & lt)] = lane + 64;
    if (u0 == T) { const int r = __popcll(e0 & lt);               if (r < rem) o[c + r] = lane; }
    if (u1 == T) { const int r = __popcll(e0) + __popcll(e1 & lt); if (r < rem) o[c + r] = lane + 64; }
}

__global__ __launch_bounds__(256) void k3_main(const float* __restrict__ feats,
        const int* __restrict__ nbr, const float* __restrict__ Wm,
        const float* __restrict__ Wo, const float* __restrict__ com,
        float* __restrict__ out)
{
    const int b = blockIdx.x, t = threadIdx.x;
    __shared__ float sF[128][8];
    __shared__ float sWm[20][64];
    __shared__ float sWo[75][3];
    __shared__ float sXs[128][68];   // padded to break bank aliasing on gathers
    __shared__ int   sNb[128][32];
    for (int i=t;i<1024;i+=256) ((float*)sF)[i]  = feats[(size_t)b*1024 + i];
    for (int i=t;i<1280;i+=256) ((float*)sWm)[i] = Wm[i];
    for (int i=t;i<225; i+=256) ((float*)sWo)[i] = Wo[i];
    for (int i=t;i<4096;i+=256) ((int*)sNb)[i]   = nbr[(size_t)b*4096 + i];
    __syncthreads();
    // Xs[n][d] = x[n](7) . Wm[0:7, d]   (src-dependent part of the msg MLP)
    for (int i=t;i<8192;i+=256) {
        const int n = i>>6, d = i&63;
        float s = 0.f;
        #pragma unroll
        for (int k=0;k<7;k++) s = fmaf(sF[n][k], sWm[k][d], s);
        sXs[n][d] = s;
    }
    __syncthreads();

    const int dsub = t & 7;          // 8 threads per node, 8 dims each
    const int ng   = t >> 3;         // 0..31 node within chunk
    const int d0   = dsub*8;
    float wc[5][8];                  // rows 15..19 (u_x,u_y,u_z,dist,pm), my columns
    #pragma unroll
    for (int r=0;r<5;r++)
        #pragma unroll
        for (int c=0;c<8;c++) wc[r][c] = sWm[15+r][d0+c];
    const float cmx = com[(size_t)b*4+0], cmy = com[(size_t)b*4+1], cmz = com[(size_t)b*4+2];

    #pragma unroll 1
    for (int ch=0; ch<4; ++ch) {
        const int n = ch*32 + ng;
        const float pdx=sF[n][0], pdy=sF[n][1], pdz=sF[n][2];
        const float mdm=sF[n][7];
        // dst-dependent part + Y0*row14 bias
        float xdb[8];
        #pragma unroll
        for (int c=0;c<8;c++) {
            float s = Y0 * sWm[14][d0+c];
            #pragma unroll
            for (int k=0;k<7;k++) s = fmaf(sF[n][k], sWm[7+k][d0+c], s);
            xdb[c] = s;
        }
        float acc[8];
        #pragma unroll
        for (int c=0;c<8;c++) acc[c]=0.f;
        float sux=0.f, suy=0.f, suz=0.f;   // sum of Y1*u over edges
        #pragma unroll 2
        for (int e=0;e<32;e++) {
            const int sidx = sNb[n][e];
            const float rx = sF[sidx][0]-pdx, ry = sF[sidx][1]-pdy, rz = sF[sidx][2]-pdz;
            const float r2 = rx*rx+ry*ry+rz*rz;
            const float dist = sqrtf(r2);
            const float inv = Y1 / fmaxf(dist, 1e-12f);
            const float ux = rx*inv, uy = ry*inv, uz = rz*inv;
            sux += ux; suy += uy; suz += uz;
            const float pm = sF[sidx][7]*mdm;
            const float* xsrow = &sXs[sidx][d0];
            #pragma unroll
            for (int c=0;c<8;c++) {
                float v = xdb[c] + xsrow[c];
                v = fmaf(ux,   wc[0][c], v);
                v = fmaf(uy,   wc[1][c], v);
                v = fmaf(uz,   wc[2][c], v);
                v = fmaf(dist, wc[3][c], v);
                v = fmaf(pm,   wc[4][c], v);
                acc[c] += fmaxf(v, 0.f);
            }
        }
        // partial output projection from my 8 agg dims
        float p0=0.f,p1=0.f,p2=0.f;
        #pragma unroll
        for (int c=0;c<8;c++) {
            const float a = acc[c]*(1.0f/32.0f);
            p0 = fmaf(a, sWo[11+d0+c][0], p0);
            p1 = fmaf(a, sWo[11+d0+c][1], p1);
            p2 = fmaf(a, sWo[11+d0+c][2], p2);
        }
        #pragma unroll
        for (int s=1;s<8;s<<=1) {
            p0 += __shfl_xor(p0, s);
            p1 += __shfl_xor(p1, s);
            p2 += __shfl_xor(p2, s);
        }
        if (dsub == 0) {
            const float vx=sF[n][3], vy=sF[n][4], vz=sF[n][5], va=sF[n][6];
            const float vinv = Y1 / fmaxf(va, 1e-12f);
            const float na0 = 2.f*Y0;
            const float na1 = sux*(1.f/32.f) + vx*vinv;
            const float na2 = suy*(1.f/32.f) + vy*vinv;
            const float na3 = suz*(1.f/32.f) + vz*vinv;
            const float x[7] = {pdx,pdy,pdz,vx,vy,vz,va};
            #pragma unroll
            for (int k=0;k<7;k++) {
                p0 = fmaf(x[k], sWo[k][0], p0);
                p1 = fmaf(x[k], sWo[k][1], p1);
                p2 = fmaf(x[k], sWo[k][2], p2);
            }
            p0 += na0*sWo[7][0] + na1*sWo[8][0] + na2*sWo[9][0] + na3*sWo[10][0];
            p1 += na0*sWo[7][1] + na1*sWo[8][1] + na2*sWo[9][1] + na3*sWo[10][1];
            p2 += na0*sWo[7][2] + na1*sWo[8][2] + na2*sWo[9][2] + na3*sWo[10][2];
            float* op = out + ((size_t)b*NN + n)*3;
            op[0] = pdx + cmx + p0;   // centered loc + com + shift = orig loc + shift
            op[1] = pdy + cmy + p1;
            op[2] = pdz + cmz + p2;
        }
    }
}

extern "C" void kernel_launch(void* const* d_in, const int* in_sizes, int n_in,
                              void* d_out, int out_size, void* d_ws, size_t ws_size,
                              hipStream_t stream)
{
    const float* in = (const float*)d_in[0];
    const float* Wm = (const float*)d_in[1];
    const float* Wo = (const float*)d_in[2];
    float* out = (float*)d_out;
    float* feats = (float*)d_ws;                       // NB*NN*8 floats
    float* com   = feats + (size_t)NB*NN*8;            // NB*4 floats
    int*   nbr   = (int*)(com + (size_t)NB*4);         // NB*NN*32 ints

    k1_prep<<<NB,       128, 0, stream>>>(in, feats, com, out);
    k2_knn <<<NB*NN/4,  256, 0, stream>>>(feats, nbr);
    k3_main<<<NB,       256, 0, stream>>>(feats, nbr, Wm, Wo, com, out);
}

// Round 4
// 219.158 us; speedup vs baseline: 1.8523x; 1.0905x over previous
//
#include <hip/hip_runtime.h>

#define NB 1024
#define NN 128
#define KK 32
#define DM 64

constexpr float Y0 = 0.28209479177387814f;
constexpr float Y1 = 0.4886025119029199f;

// ws layout (floats):
//   feats: [NB*NN][8]  (px,py,pz,vx,vy,vz,|v|,mass)   4 MB
//   com:   [NB][4]                                     16 KB
//   nbr:   [NB*NN][32] (int)                           16 MB

__global__ __launch_bounds__(128) void k1_prep(const float* __restrict__ in,
        float* __restrict__ feats, float* __restrict__ com, float* __restrict__ out)
{
    const int b = blockIdx.x, t = threadIdx.x;
    const float* p = in + ((size_t)b*NN + t)*7;
    const float m  = p[0];
    const float lx = p[1], ly = p[2], lz = p[3];
    const float vx = p[4], vy = p[5], vz = p[6];
    float w=m, wx=m*lx, wy=m*ly, wz=m*lz;
    #pragma unroll
    for (int s=1; s<64; s<<=1) {
        w  += __shfl_xor(w,  s);
        wx += __shfl_xor(wx, s);
        wy += __shfl_xor(wy, s);
        wz += __shfl_xor(wz, s);
    }
    __shared__ float red[2][4];
    if ((t & 63) == 0) { int wi=t>>6; red[wi][0]=w; red[wi][1]=wx; red[wi][2]=wy; red[wi][3]=wz; }
    __syncthreads();
    const float Wt = red[0][0]+red[1][0];
    const float cx = (red[0][1]+red[1][1])/Wt;
    const float cy = (red[0][2]+red[1][2])/Wt;
    const float cz = (red[0][3]+red[1][3])/Wt;
    const float px = lx-cx, py = ly-cy, pz = lz-cz;
    const float va = sqrtf(vx*vx+vy*vy+vz*vz);
    float4* f4 = (float4*)(feats + ((size_t)b*NN + t)*8);
    f4[0] = make_float4(px,py,pz,vx);
    f4[1] = make_float4(vy,vz,va,m);
    if (t==0) { float4* c4=(float4*)(com + (size_t)b*4); *c4 = make_float4(cx,cy,cz,0.f); }
    // second output: zeros(B)
    if (b < 8) out[(size_t)NB*NN*3 + (size_t)b*128 + t] = 0.f;
}

// block = batch: 4 waves, each wave does 32 nodes with 2-node ILP ballot search.
__global__ __launch_bounds__(256) void k2_knn(const float* __restrict__ feats,
                                              int* __restrict__ nbr)
{
    const int b = blockIdx.x, t = threadIdx.x;
    const int lane = t & 63, w = t >> 6;
    __shared__ float4 sP[128];
    if (t < 128) sP[t] = *(const float4*)(feats + ((size_t)b*NN + t)*8);
    __syncthreads();
    const float4 A4 = sP[lane];
    const float4 B4 = sP[lane+64];
    const float INF = __int_as_float(0x7f800000);
    const unsigned long long lt = (1ULL<<lane)-1ULL;
    #pragma unroll 1
    for (int i=0; i<32; i+=2) {
        const int n0 = w*32 + i, n1 = n0+1;
        const float4 C0 = sP[n0], C1 = sP[n1];
        float dx,dy,dz;
        dx=A4.x-C0.x; dy=A4.y-C0.y; dz=A4.z-C0.z;
        float d2a0 = dx*dx+dy*dy+dz*dz;
        dx=B4.x-C0.x; dy=B4.y-C0.y; dz=B4.z-C0.z;
        float d2b0 = dx*dx+dy*dy+dz*dz;
        dx=A4.x-C1.x; dy=A4.y-C1.y; dz=A4.z-C1.z;
        float d2a1 = dx*dx+dy*dy+dz*dz;
        dx=B4.x-C1.x; dy=B4.y-C1.y; dz=B4.z-C1.z;
        float d2b1 = dx*dx+dy*dy+dz*dz;
        if (lane    == n0) d2a0 = INF;
        if (lane+64 == n0) d2b0 = INF;
        if (lane    == n1) d2a1 = INF;
        if (lane+64 == n1) d2b1 = INF;
        const unsigned ua0=__float_as_uint(d2a0), ub0=__float_as_uint(d2b0);
        const unsigned ua1=__float_as_uint(d2a1), ub1=__float_as_uint(d2b1);
        unsigned P0=0u, P1=0u;
        #pragma unroll 1
        for (int bit=30;bit>=0;--bit) {
            const unsigned Q0=P0|(1u<<bit), Q1=P1|(1u<<bit);
            const int c0 = __popcll(__ballot(ua0<Q0)) + __popcll(__ballot(ub0<Q0));
            const int c1 = __popcll(__ballot(ua1<Q1)) + __popcll(__ballot(ub1<Q1));
            if (c0<=31) P0=Q0;
            if (c1<=31) P1=Q1;
        }
        {
            const unsigned long long m0=__ballot(ua0<P0), m1=__ballot(ub0<P0);
            const unsigned long long e0=__ballot(ua0==P0), e1=__ballot(ub0==P0);
            const int c0n=__popcll(m0), c=c0n+__popcll(m1), rem=32-c;
            int* row = nbr + ((size_t)b*NN + n0)*32;
            if (ua0< P0) row[__popcll(m0&lt)] = lane;
            if (ub0< P0) row[c0n+__popcll(m1&lt)] = lane+64;
            if (ua0==P0) { const int r=__popcll(e0&lt);               if (r<rem) row[c+r]=lane; }
            if (ub0==P0) { const int r=__popcll(e0)+__popcll(e1&lt);  if (r<rem) row[c+r]=lane+64; }
        }
        {
            const unsigned long long m0=__ballot(ua1<P1), m1=__ballot(ub1<P1);
            const unsigned long long e0=__ballot(ua1==P1), e1=__ballot(ub1==P1);
            const int c0n=__popcll(m0), c=c0n+__popcll(m1), rem=32-c;
            int* row = nbr + ((size_t)b*NN + n1)*32;
            if (ua1< P1) row[__popcll(m0&lt)] = lane;
            if (ub1< P1) row[c0n+__popcll(m1&lt)] = lane+64;
            if (ua1==P1) { const int r=__popcll(e0&lt);               if (r<rem) row[c+r]=lane; }
            if (ub1==P1) { const int r=__popcll(e0)+__popcll(e1&lt);  if (r<rem) row[c+r]=lane+64; }
        }
    }
}

__global__ __launch_bounds__(256) void k3_main(const float* __restrict__ feats,
        const int* __restrict__ nbr, const float* __restrict__ Wm,
        const float* __restrict__ Wo, const float* __restrict__ com,
        float* __restrict__ out)
{
    const int b = blockIdx.x, t = threadIdx.x;
    __shared__ float4 sPos[128];                     // {px,py,pz,mass}
    __shared__ float4 sVel[128];                     // {vx,vy,vz,|v|}
    __shared__ __align__(16) float sXs[128*64];      // quad-XOR swizzled
    __shared__ float  sWm[20][64];
    __shared__ float  sWo[75][3];
    __shared__ float4 sE4[32][33];                   // {Y1*ux,Y1*uy,Y1*uz,dist}, padded
    __shared__ float  sPm[32][33];                   // prod_mass, padded
    __shared__ int    sSrc[32][33];                  // src node id, padded
    __shared__ float4 sSu[32];                       // per-node sum of Y1*u

    for (int i=t;i<1280;i+=256) ((float*)sWm)[i] = Wm[i];
    for (int i=t;i<225; i+=256) ((float*)sWo)[i] = Wo[i];
    if (t < 128) {
        const float4* f4 = (const float4*)(feats + ((size_t)b*NN + t)*8);
        sPos[t] = f4[0];   // px,py,pz,vx  -> fix below
        sVel[t] = f4[1];   // vy,vz,va,m
    }
    __syncthreads();
    // repack: sPos={px,py,pz,m}, sVel={vx,vy,vz,va}
    if (t < 128) {
        const float4 a = sPos[t], c = sVel[t];
        // a = {px,py,pz,vx}, c = {vy,vz,va,m}
        sPos[t] = make_float4(a.x,a.y,a.z,c.w);
        sVel[t] = make_float4(a.w,c.x,c.y,c.z);
    }
    __syncthreads();

    // Xs[n][d] = x[n](7) . Wm[0:7,d], swizzled store
    for (int i=t;i<8192;i+=256) {
        const int n = i>>6, d = i&63;
        const float4 P = sPos[n], V = sVel[n];
        float s = P.x*sWm[0][d];
        s = fmaf(P.y, sWm[1][d], s);
        s = fmaf(P.z, sWm[2][d], s);
        s = fmaf(V.x, sWm[3][d], s);
        s = fmaf(V.y, sWm[4][d], s);
        s = fmaf(V.z, sWm[5][d], s);
        s = fmaf(V.w, sWm[6][d], s);
        const int q = d>>2;
        sXs[(n<<6) + ((q ^ (n&7))<<2) + (d&3)] = s;
    }
    __syncthreads();

    const int dsub = t & 7, ng = t >> 3, d0 = dsub*8, q0 = dsub*2;
    float wc[5][8];
    #pragma unroll
    for (int r=0;r<5;r++)
        #pragma unroll
        for (int c=0;c<8;c++) wc[r][c] = sWm[15+r][d0+c];
    const float cmx = com[(size_t)b*4+0], cmy = com[(size_t)b*4+1], cmz = com[(size_t)b*4+2];

    #pragma unroll 1
    for (int ch=0; ch<4; ++ch) {
        // ---- edge-table build: 1024 edges, each computed once ----
        {
            const int nl = t>>3, j0 = (t&7)*4;
            const int n  = ch*32 + nl;
            const float4 Pn = sPos[n];
            const int4 nb4 = *(const int4*)(nbr + ((size_t)b*NN + n)*32 + j0);
            const int js[4] = {nb4.x, nb4.y, nb4.z, nb4.w};
            float sx=0.f, sy=0.f, sz=0.f;
            #pragma unroll
            for (int r=0;r<4;r++) {
                const int s = js[r];
                const float4 Ps = sPos[s];
                const float rx=Ps.x-Pn.x, ry=Ps.y-Pn.y, rz=Ps.z-Pn.z;
                const float dist = sqrtf(rx*rx+ry*ry+rz*rz);
                const float inv  = Y1 * __builtin_amdgcn_rcpf(fmaxf(dist,1e-12f));
                const float ux=rx*inv, uy=ry*inv, uz=rz*inv;
                sx+=ux; sy+=uy; sz+=uz;
                sE4[nl][j0+r] = make_float4(ux,uy,uz,dist);
                sPm[nl][j0+r] = Ps.w*Pn.w;
                sSrc[nl][j0+r] = s;
            }
            #pragma unroll
            for (int s=1;s<8;s<<=1) { sx+=__shfl_xor(sx,s); sy+=__shfl_xor(sy,s); sz+=__shfl_xor(sz,s); }
            if ((t&7)==0) sSu[nl] = make_float4(sx,sy,sz,0.f);
        }
        __syncthreads();

        // ---- main: per-node message accumulation over 32 edges ----
        {
            const int n = ch*32 + ng;
            const float4 Pn = sPos[n], Vn = sVel[n];
            float xdb[8];
            #pragma unroll
            for (int c=0;c<8;c++) {
                float s = Y0 * sWm[14][d0+c];
                s = fmaf(Pn.x, sWm[7][d0+c], s);
                s = fmaf(Pn.y, sWm[8][d0+c], s);
                s = fmaf(Pn.z, sWm[9][d0+c], s);
                s = fmaf(Vn.x, sWm[10][d0+c], s);
                s = fmaf(Vn.y, sWm[11][d0+c], s);
                s = fmaf(Vn.z, sWm[12][d0+c], s);
                s = fmaf(Vn.w, sWm[13][d0+c], s);
                xdb[c] = s;
            }
            float acc[8];
            #pragma unroll
            for (int c=0;c<8;c++) acc[c]=0.f;
            #pragma unroll 8
            for (int e=0;e<32;e++) {
                const float4 E = sE4[ng][e];
                const float pm = sPm[ng][e];
                const int s = sSrc[ng][e];
                const int a0 = (s<<8) + ((q0 ^ (s&7))<<4);
                const float4 xsA = *(const float4*)((const char*)sXs + a0);
                const float4 xsB = *(const float4*)((const char*)sXs + (a0^16));
                const float xs[8] = {xsA.x,xsA.y,xsA.z,xsA.w, xsB.x,xsB.y,xsB.z,xsB.w};
                #pragma unroll
                for (int c=0;c<8;c++) {
                    float v = xdb[c] + xs[c];
                    v = fmaf(E.x, wc[0][c], v);
                    v = fmaf(E.y, wc[1][c], v);
                    v = fmaf(E.z, wc[2][c], v);
                    v = fmaf(E.w, wc[3][c], v);
                    v = fmaf(pm,  wc[4][c], v);
                    acc[c] += fmaxf(v, 0.f);
                }
            }
            float p0=0.f,p1=0.f,p2=0.f;
            #pragma unroll
            for (int c=0;c<8;c++) {
                const float a = acc[c]*(1.0f/32.0f);
                p0 = fmaf(a, sWo[11+d0+c][0], p0);
                p1 = fmaf(a, sWo[11+d0+c][1], p1);
                p2 = fmaf(a, sWo[11+d0+c][2], p2);
            }
            #pragma unroll
            for (int s=1;s<8;s<<=1) {
                p0 += __shfl_xor(p0,s); p1 += __shfl_xor(p1,s); p2 += __shfl_xor(p2,s);
            }
            if (dsub == 0) {
                const float4 Su = sSu[ng];
                const float vinv = Y1 * __builtin_amdgcn_rcpf(fmaxf(Vn.w,1e-12f));
                const float na0 = 2.f*Y0;
                const float na1 = Su.x*(1.f/32.f) + Vn.x*vinv;
                const float na2 = Su.y*(1.f/32.f) + Vn.y*vinv;
                const float na3 = Su.z*(1.f/32.f) + Vn.z*vinv;
                const float xf[7] = {Pn.x,Pn.y,Pn.z,Vn.x,Vn.y,Vn.z,Vn.w};
                #pragma unroll
                for (int k=0;k<7;k++) {
                    p0 = fmaf(xf[k], sWo[k][0], p0);
                    p1 = fmaf(xf[k], sWo[k][1], p1);
                    p2 = fmaf(xf[k], sWo[k][2], p2);
                }
                p0 += na0*sWo[7][0] + na1*sWo[8][0] + na2*sWo[9][0] + na3*sWo[10][0];
                p1 += na0*sWo[7][1] + na1*sWo[8][1] + na2*sWo[9][1] + na3*sWo[10][1];
                p2 += na0*sWo[7][2] + na1*sWo[8][2] + na2*sWo[9][2] + na3*sWo[10][2];
                float* op = out + ((size_t)b*NN + n)*3;
                op[0] = Pn.x + cmx + p0;
                op[1] = Pn.y + cmy + p1;
                op[2] = Pn.z + cmz + p2;
            }
        }
        __syncthreads();   // full separation: next build's writes vs this main's reads
    }
}

extern "C" void kernel_launch(void* const* d_in, const int* in_sizes, int n_in,
                              void* d_out, int out_size, void* d_ws, size_t ws_size,
                              hipStream_t stream)
{
    const float* in = (const float*)d_in[0];
    const float* Wm = (const float*)d_in[1];
    const float* Wo = (const float*)d_in[2];
    float* out = (float*)d_out;
    float* feats = (float*)d_ws;                       // NB*NN*8 floats
    float* com   = feats + (size_t)NB*NN*8;            // NB*4 floats
    int*   nbr   = (int*)(com + (size_t)NB*4);         // NB*NN*32 ints

    k1_prep<<<NB, 128, 0, stream>>>(in, feats, com, out);
    k2_knn <<<NB, 256, 0, stream>>>(feats, nbr);
    k3_main<<<NB, 256, 0, stream>>>(feats, nbr, Wm, Wo, com, out);
}

// Round 5
// 198.753 us; speedup vs baseline: 2.0425x; 1.1027x over previous
//
#include <hip/hip_runtime.h>

#define NB 1024
#define NN 128
#define KK 32
#define DM 64

constexpr float Y0 = 0.28209479177387814f;
constexpr float Y1 = 0.4886025119029199f;

typedef float f2 __attribute__((ext_vector_type(2)));

// ws layout (floats):
//   feats: [NB*NN][8]  (px,py,pz,vx,vy,vz,|v|,mass)   4 MB
//   com:   [NB][4]                                     16 KB
//   nbr:   [NB*NN][32] (int)                           16 MB

// merged: com + centered features + exact 32-NN (ballot radix search, ILP-4)
__global__ __launch_bounds__(256) void k12_prep_knn(const float* __restrict__ in,
        float* __restrict__ feats, float* __restrict__ com, int* __restrict__ nbr,
        float* __restrict__ out)
{
    const int b = blockIdx.x, t = threadIdx.x;
    const int lane = t & 63, w = t >> 6;
    __shared__ float4 sP[128];
    __shared__ float red[2][4];

    float m=0.f,lx=0.f,ly=0.f,lz=0.f,vx=0.f,vy=0.f,vz=0.f;
    if (t < 128) {
        const float* p = in + ((size_t)b*NN + t)*7;
        m=p[0]; lx=p[1]; ly=p[2]; lz=p[3]; vx=p[4]; vy=p[5]; vz=p[6];
    }
    {
        float sw=m, sx=m*lx, sy=m*ly, sz=m*lz;
        #pragma unroll
        for (int s=1;s<64;s<<=1) {
            sw+=__shfl_xor(sw,s); sx+=__shfl_xor(sx,s);
            sy+=__shfl_xor(sy,s); sz+=__shfl_xor(sz,s);
        }
        if (t<128 && lane==0) { red[w][0]=sw; red[w][1]=sx; red[w][2]=sy; red[w][3]=sz; }
    }
    if (t==0) out[(size_t)NB*NN*3 + b] = 0.f;   // second output: zeros(B)
    __syncthreads();
    const float Wt  = red[0][0]+red[1][0];
    const float cmx = (red[0][1]+red[1][1])/Wt;
    const float cmy = (red[0][2]+red[1][2])/Wt;
    const float cmz = (red[0][3]+red[1][3])/Wt;
    if (t < 128) {
        const float px=lx-cmx, py=ly-cmy, pz=lz-cmz;
        const float va = sqrtf(vx*vx+vy*vy+vz*vz);
        sP[t] = make_float4(px,py,pz,m);
        float4* f4 = (float4*)(feats + ((size_t)b*NN + t)*8);
        f4[0] = make_float4(px,py,pz,vx);
        f4[1] = make_float4(vy,vz,va,m);
        if (t==0) { float4* c4=(float4*)(com + (size_t)b*4); *c4 = make_float4(cmx,cmy,cmz,0.f); }
    }
    __syncthreads();

    // wave w owns nodes w*32 .. w*32+31, processed 4 at a time (ILP-4 chains)
    const float4 A4 = sP[lane];
    const float4 B4 = sP[lane+64];
    const float INF = __int_as_float(0x7f800000);
    const unsigned long long lt = (1ULL<<lane)-1ULL;
    #pragma unroll 1
    for (int i=0; i<32; i+=4) {
        const int nb0 = w*32 + i;
        unsigned ua[4], ub[4], P[4];
        #pragma unroll
        for (int k=0;k<4;k++) {
            const int n = nb0 + k;
            const float4 C = sP[n];
            float dx=A4.x-C.x, dy=A4.y-C.y, dz=A4.z-C.z;
            float d2a = dx*dx+dy*dy+dz*dz;
            dx=B4.x-C.x; dy=B4.y-C.y; dz=B4.z-C.z;
            float d2b = dx*dx+dy*dy+dz*dz;
            if (lane    == n) d2a = INF;
            if (lane+64 == n) d2b = INF;
            ua[k]=__float_as_uint(d2a); ub[k]=__float_as_uint(d2b);
            P[k]=0u;
        }
        #pragma unroll 1
        for (int bit=30;bit>=0;--bit) {
            const unsigned msk = 1u<<bit;
            #pragma unroll
            for (int k=0;k<4;k++) {
                const unsigned Q = P[k]|msk;
                const int cnt = __popcll(__ballot(ua[k]<Q)) + __popcll(__ballot(ub[k]<Q));
                if (cnt<=31) P[k]=Q;
            }
        }
        #pragma unroll
        for (int k=0;k<4;k++) {
            const unsigned T = P[k];
            const unsigned long long m0=__ballot(ua[k]<T), m1=__ballot(ub[k]<T);
            const unsigned long long e0=__ballot(ua[k]==T), e1=__ballot(ub[k]==T);
            const int c0n=__popcll(m0), c=c0n+__popcll(m1), rem=32-c;
            int* row = nbr + ((size_t)b*NN + nb0 + k)*32;
            if (ua[k]< T) row[__popcll(m0&lt)] = lane;
            if (ub[k]< T) row[c0n+__popcll(m1&lt)] = lane+64;
            if (ua[k]==T) { const int r=__popcll(e0&lt);               if (r<rem) row[c+r]=lane; }
            if (ub[k]==T) { const int r=__popcll(e0)+__popcll(e1&lt);  if (r<rem) row[c+r]=lane+64; }
        }
    }
}

__global__ __launch_bounds__(256) void k3_main(const float* __restrict__ feats,
        const int* __restrict__ nbr, const float* __restrict__ Wm,
        const float* __restrict__ Wo, const float* __restrict__ com,
        float* __restrict__ out)
{
    const int b = blockIdx.x, t = threadIdx.x;
    __shared__ float4 sPos[128];                     // {px,py,pz,mass}
    __shared__ float4 sVel[128];                     // {vx,vy,vz,|v|}
    __shared__ __align__(16) float sXs[128*64];      // quad-XOR swizzled
    __shared__ float  sWm[20][64];
    __shared__ float  sWo[75][3];
    __shared__ float4 sE4[32][33];                   // {Y1*ux,Y1*uy,Y1*uz,dist}, padded
    __shared__ float  sPm[32][33];                   // prod_mass, padded
    __shared__ int    sSrc[32][33];                  // src node id, padded
    __shared__ float4 sSu[32];                       // per-node sum of Y1*u

    for (int i=t;i<1280;i+=256) ((float*)sWm)[i] = Wm[i];
    for (int i=t;i<225; i+=256) ((float*)sWo)[i] = Wo[i];
    if (t < 128) {
        const float4* f4 = (const float4*)(feats + ((size_t)b*NN + t)*8);
        sPos[t] = f4[0];   // px,py,pz,vx  -> repacked below
        sVel[t] = f4[1];   // vy,vz,va,m
    }
    __syncthreads();
    if (t < 128) {
        const float4 a = sPos[t], c = sVel[t];
        sPos[t] = make_float4(a.x,a.y,a.z,c.w);
        sVel[t] = make_float4(a.w,c.x,c.y,c.z);
    }
    __syncthreads();

    // Xs[n][d] = x[n](7) . Wm[0:7,d], swizzled store
    for (int i=t;i<8192;i+=256) {
        const int n = i>>6, d = i&63;
        const float4 P = sPos[n], V = sVel[n];
        float s = P.x*sWm[0][d];
        s = fmaf(P.y, sWm[1][d], s);
        s = fmaf(P.z, sWm[2][d], s);
        s = fmaf(V.x, sWm[3][d], s);
        s = fmaf(V.y, sWm[4][d], s);
        s = fmaf(V.z, sWm[5][d], s);
        s = fmaf(V.w, sWm[6][d], s);
        const int q = d>>2;
        sXs[(n<<6) + ((q ^ (n&7))<<2) + (d&3)] = s;
    }
    __syncthreads();

    const int dsub = t & 7, ng = t >> 3, d0 = dsub*8, q0 = dsub*2;
    f2 wc2[5][4];
    #pragma unroll
    for (int r=0;r<5;r++)
        #pragma unroll
        for (int j=0;j<4;j++) {
            wc2[r][j].x = sWm[15+r][d0+2*j];
            wc2[r][j].y = sWm[15+r][d0+2*j+1];
        }
    const float cmx = com[(size_t)b*4+0], cmy = com[(size_t)b*4+1], cmz = com[(size_t)b*4+2];

    #pragma unroll 1
    for (int ch=0; ch<4; ++ch) {
        // ---- edge-table build: 1024 edges, each computed once ----
        {
            const int nl = t>>3, j0 = (t&7)*4;
            const int n  = ch*32 + nl;
            const float4 Pn = sPos[n];
            const int4 nb4 = *(const int4*)(nbr + ((size_t)b*NN + n)*32 + j0);
            const int js[4] = {nb4.x, nb4.y, nb4.z, nb4.w};
            float sx=0.f, sy=0.f, sz=0.f;
            #pragma unroll
            for (int r=0;r<4;r++) {
                const int s = js[r];
                const float4 Ps = sPos[s];
                const float rx=Ps.x-Pn.x, ry=Ps.y-Pn.y, rz=Ps.z-Pn.z;
                const float dist = sqrtf(rx*rx+ry*ry+rz*rz);
                const float inv  = Y1 * __builtin_amdgcn_rcpf(fmaxf(dist,1e-12f));
                const float ux=rx*inv, uy=ry*inv, uz=rz*inv;
                sx+=ux; sy+=uy; sz+=uz;
                sE4[nl][j0+r] = make_float4(ux,uy,uz,dist);
                sPm[nl][j0+r] = Ps.w*Pn.w;
                sSrc[nl][j0+r] = s;
            }
            #pragma unroll
            for (int s=1;s<8;s<<=1) { sx+=__shfl_xor(sx,s); sy+=__shfl_xor(sy,s); sz+=__shfl_xor(sz,s); }
            if ((t&7)==0) sSu[nl] = make_float4(sx,sy,sz,0.f);
        }
        __syncthreads();

        // ---- main: per-node message accumulation over 32 edges (packed fp32) ----
        {
            const int n = ch*32 + ng;
            const float4 Pn = sPos[n], Vn = sVel[n];
            f2 xdb2[4];
            #pragma unroll
            for (int j=0;j<4;j++) {
                #pragma unroll
                for (int h=0;h<2;h++) {
                    const int c = 2*j+h;
                    float s = Y0 * sWm[14][d0+c];
                    s = fmaf(Pn.x, sWm[7][d0+c], s);
                    s = fmaf(Pn.y, sWm[8][d0+c], s);
                    s = fmaf(Pn.z, sWm[9][d0+c], s);
                    s = fmaf(Vn.x, sWm[10][d0+c], s);
                    s = fmaf(Vn.y, sWm[11][d0+c], s);
                    s = fmaf(Vn.z, sWm[12][d0+c], s);
                    s = fmaf(Vn.w, sWm[13][d0+c], s);
                    if (h==0) xdb2[j].x = s; else xdb2[j].y = s;
                }
            }
            f2 acc2[4];
            #pragma unroll
            for (int j=0;j<4;j++) acc2[j] = (f2){0.f,0.f};
            const f2 zero2 = (f2){0.f,0.f};
            #pragma unroll 8
            for (int e=0;e<32;e++) {
                const float4 E = sE4[ng][e];
                const float pm = sPm[ng][e];
                const int s = sSrc[ng][e];
                const int a0 = (s<<8) + ((q0 ^ (s&7))<<4);
                const float4 xsA = *(const float4*)((const char*)sXs + a0);
                const float4 xsB = *(const float4*)((const char*)sXs + (a0^16));
                f2 xs2[4];
                xs2[0] = (f2){xsA.x, xsA.y};
                xs2[1] = (f2){xsA.z, xsA.w};
                xs2[2] = (f2){xsB.x, xsB.y};
                xs2[3] = (f2){xsB.z, xsB.w};
                const f2 ex = (f2){E.x, E.x};
                const f2 ey = (f2){E.y, E.y};
                const f2 ez = (f2){E.z, E.z};
                const f2 ew = (f2){E.w, E.w};
                const f2 pm2 = (f2){pm, pm};
                #pragma unroll
                for (int j=0;j<4;j++) {
                    f2 v = xdb2[j] + xs2[j];
                    v = __builtin_elementwise_fma(ex,  wc2[0][j], v);
                    v = __builtin_elementwise_fma(ey,  wc2[1][j], v);
                    v = __builtin_elementwise_fma(ez,  wc2[2][j], v);
                    v = __builtin_elementwise_fma(ew,  wc2[3][j], v);
                    v = __builtin_elementwise_fma(pm2, wc2[4][j], v);
                    v = __builtin_elementwise_max(v, zero2);
                    acc2[j] += v;
                }
            }
            float p0=0.f,p1=0.f,p2=0.f;
            #pragma unroll
            for (int j=0;j<4;j++) {
                const float a0v = acc2[j].x*(1.0f/32.0f);
                const float a1v = acc2[j].y*(1.0f/32.0f);
                const int c0 = 2*j, c1 = 2*j+1;
                p0 = fmaf(a0v, sWo[11+d0+c0][0], p0);
                p1 = fmaf(a0v, sWo[11+d0+c0][1], p1);
                p2 = fmaf(a0v, sWo[11+d0+c0][2], p2);
                p0 = fmaf(a1v, sWo[11+d0+c1][0], p0);
                p1 = fmaf(a1v, sWo[11+d0+c1][1], p1);
                p2 = fmaf(a1v, sWo[11+d0+c1][2], p2);
            }
            #pragma unroll
            for (int s=1;s<8;s<<=1) {
                p0 += __shfl_xor(p0,s); p1 += __shfl_xor(p1,s); p2 += __shfl_xor(p2,s);
            }
            if (dsub == 0) {
                const float4 Su = sSu[ng];
                const float vinv = Y1 * __builtin_amdgcn_rcpf(fmaxf(Vn.w,1e-12f));
                const float na0 = 2.f*Y0;
                const float na1 = Su.x*(1.f/32.f) + Vn.x*vinv;
                const float na2 = Su.y*(1.f/32.f) + Vn.y*vinv;
                const float na3 = Su.z*(1.f/32.f) + Vn.z*vinv;
                const float xf[7] = {Pn.x,Pn.y,Pn.z,Vn.x,Vn.y,Vn.z,Vn.w};
                #pragma unroll
                for (int k=0;k<7;k++) {
                    p0 = fmaf(xf[k], sWo[k][0], p0);
                    p1 = fmaf(xf[k], sWo[k][1], p1);
                    p2 = fmaf(xf[k], sWo[k][2], p2);
                }
                p0 += na0*sWo[7][0] + na1*sWo[8][0] + na2*sWo[9][0] + na3*sWo[10][0];
                p1 += na0*sWo[7][1] + na1*sWo[8][1] + na2*sWo[9][1] + na3*sWo[10][1];
                p2 += na0*sWo[7][2] + na1*sWo[8][2] + na2*sWo[9][2] + na3*sWo[10][2];
                float* op = out + ((size_t)b*NN + n)*3;
                op[0] = Pn.x + cmx + p0;
                op[1] = Pn.y + cmy + p1;
                op[2] = Pn.z + cmz + p2;
            }
        }
        __syncthreads();   // full separation: next build's writes vs this main's reads
    }
}

extern "C" void kernel_launch(void* const* d_in, const int* in_sizes, int n_in,
                              void* d_out, int out_size, void* d_ws, size_t ws_size,
                              hipStream_t stream)
{
    const float* in = (const float*)d_in[0];
    const float* Wm = (const float*)d_in[1];
    const float* Wo = (const float*)d_in[2];
    float* out = (float*)d_out;
    float* feats = (float*)d_ws;                       // NB*NN*8 floats
    float* com   = feats + (size_t)NB*NN*8;            // NB*4 floats
    int*   nbr   = (int*)(com + (size_t)NB*4);         // NB*NN*32 ints

    k12_prep_knn<<<NB, 256, 0, stream>>>(in, feats, com, nbr, out);
    k3_main     <<<NB, 256, 0, stream>>>(feats, nbr, Wm, Wo, com, out);
}